// Round 2
// baseline (371.299 us; speedup 1.0000x reference)
//
#include <hip/hip_runtime.h>

#define Bn 8
#define Tn 4096
#define Dn 256
#define Mn (Bn*Tn)           // 32768

typedef short bf16x8 __attribute__((ext_vector_type(8)));
typedef float f32x4 __attribute__((ext_vector_type(4)));

__device__ __forceinline__ unsigned short f2bf(float f) {
    union { float f; unsigned int u; } v; v.f = f;
    unsigned int r = v.u + 0x7fffu + ((v.u >> 16) & 1u);
    return (unsigned short)(r >> 16);
}

// ---------------- cast x (f32 -> bf16), 8 elems/thread ----------------
__global__ void __launch_bounds__(256) cast_x_kernel(const float* __restrict__ x,
                                                     unsigned short* __restrict__ xb) {
    size_t i = (size_t)blockIdx.x * 256 + threadIdx.x;
    const float4* p = reinterpret_cast<const float4*>(x) + i * 2;
    float4 a = p[0], b = p[1];
    union { unsigned short u[8]; uint4 v; } o;
    o.u[0]=f2bf(a.x); o.u[1]=f2bf(a.y); o.u[2]=f2bf(a.z); o.u[3]=f2bf(a.w);
    o.u[4]=f2bf(b.x); o.u[5]=f2bf(b.y); o.u[6]=f2bf(b.z); o.u[7]=f2bf(b.w);
    reinterpret_cast<uint4*>(xb)[i] = o.v;
}

// ---------------- W transpose+cast: Wt[h][n][k] = W_h[k][n] ----------------
__global__ void __launch_bounds__(256) wt_kernel(const float* __restrict__ wq,
                                                 const float* __restrict__ wk,
                                                 const float* __restrict__ wv,
                                                 unsigned short* __restrict__ wt) {
    int idx = blockIdx.x * 256 + threadIdx.x;
    int h = idx >> 16; int r = idx & 65535;
    int k = r >> 8, n = r & 255;
    const float* src = (h == 0) ? wq : (h == 1) ? wk : wv;
    wt[h * 65536 + n * 256 + k] = f2bf(src[k * 256 + n]);
}

// ---------------- projection GEMM ----------------
// h=0: Q row-major [M][256]; h=1: K row-major; h=2: V TRANSPOSED [256][M]
__global__ void __launch_bounds__(256, 2) proj_kernel(const unsigned short* __restrict__ xb,
                                                      const unsigned short* __restrict__ wt,
                                                      unsigned short* __restrict__ qkv) {
    __shared__ unsigned short wlds[256 * 40];
    int h = blockIdx.y;
    const unsigned short* wth = wt + h * 65536;
    int m0 = blockIdx.x * 64;
    int tid = threadIdx.x;
    int w = tid >> 6, lane = tid & 63;
    int c = lane & 15, g = lane >> 4;
    size_t arow = (size_t)(m0 + w * 16 + c);

    const f32x4 fz = {0.f, 0.f, 0.f, 0.f};
    f32x4 acc[16];
#pragma unroll
    for (int n = 0; n < 16; n++) acc[n] = fz;

    for (int kk = 0; kk < 8; kk++) {
        __syncthreads();
#pragma unroll
        for (int p = 0; p < 4; p++) {
            int idx = p * 256 + tid;
            int r = idx >> 2, ch = idx & 3;
            bf16x8 v = *(const bf16x8*)(wth + r * 256 + kk * 32 + ch * 8);
            *(bf16x8*)(&wlds[r * 40 + ch * 8]) = v;
        }
        __syncthreads();
        bf16x8 af = *(const bf16x8*)(xb + arow * Dn + kk * 32 + g * 8);
#pragma unroll
        for (int n = 0; n < 16; n++) {
            bf16x8 bfv = *(const bf16x8*)(&wlds[(n * 16 + c) * 40 + g * 8]);
            acc[n] = __builtin_amdgcn_mfma_f32_16x16x32_bf16(af, bfv, acc[n], 0, 0, 0);
        }
    }
    int orow0 = m0 + w * 16 + g * 4;
    if (h < 2) {
        unsigned short* out = qkv + (size_t)h * Mn * Dn;
#pragma unroll
        for (int n = 0; n < 16; n++)
#pragma unroll
            for (int r = 0; r < 4; r++)
                out[(size_t)(orow0 + r) * Dn + n * 16 + c] = f2bf(acc[n][r]);
    } else {
        unsigned short* vt = qkv + (size_t)2 * Mn * Dn;   // [256][M]
#pragma unroll
        for (int n = 0; n < 16; n++) {
            union { unsigned short u[4]; ushort4 v4; } pk;
#pragma unroll
            for (int r = 0; r < 4; r++) pk.u[r] = f2bf(acc[n][r]);
            *(ushort4*)(vt + (size_t)(n * 16 + c) * Mn + orow0) = pk.v4;
        }
    }
}

// ---------------- causal flash attention (swapped-operand, KVBLK=64) ----------------
__global__ void __launch_bounds__(256, 2) attn_kernel(const unsigned short* __restrict__ qkv,
                                                      float* __restrict__ outp) {
    __shared__ char smem[65536];
    char* klds = smem;            // K tile [64][256] bf16, XOR-swizzled
    char* vlds = smem + 32768;    // V^T tile [256][64] bf16, XOR-swizzled

    int blk = blockIdx.x;
    int half = blk >> 8, rr = blk & 255;
    int b = rr & 7;
    int qt = rr >> 3; if (half) qt = 63 - qt;
    int q0 = qt * 64;

    int tid = threadIdx.x, w = tid >> 6, lane = tid & 63;
    int c = lane & 15, g = lane >> 4;

    const unsigned short* Qg = qkv;
    const unsigned short* Kg = qkv + (size_t)Mn * Dn;
    const unsigned short* Vt = qkv + (size_t)2 * Mn * Dn;

    int qrow = q0 + w * 16;
    size_t qbase = (size_t)b * Tn + qrow;
    int qg_lane = qrow + c;                 // this lane's q row (within batch)

    bf16x8 qf[8];
#pragma unroll
    for (int kk = 0; kk < 8; kk++)
        qf[kk] = *(const bf16x8*)(Qg + (qbase + c) * Dn + kk * 32 + g * 8);

    const f32x4 fz = {0.f, 0.f, 0.f, 0.f};
    f32x4 o[16];
#pragma unroll
    for (int n = 0; n < 16; n++) o[n] = fz;
    float m2 = -INFINITY, l = 0.f;

    const int krow_base = tid >> 5;         // + p*8, row 0..63
    const int kch = tid & 31;               // 8-elem chunk in 256 row
    const int vf_base = tid >> 3;           // + p*32, f 0..255
    const int vch = tid & 7;                // 8-elem chunk in 64 row

    bf16x8 kreg[8], vreg[8];
    const float C1 = 0.09016844005555897f;  // 0.0625 * log2(e)

    auto LOADT = [&](int t) {
        size_t kgbase = ((size_t)b * Tn + t * 64) * Dn;
        size_t vgbase = (size_t)b * Tn + t * 64;
#pragma unroll
        for (int p = 0; p < 8; p++) {
            int r = p * 8 + krow_base;
            kreg[p] = *(const bf16x8*)(Kg + kgbase + (size_t)r * Dn + kch * 8);
        }
#pragma unroll
        for (int p = 0; p < 8; p++) {
            int f = p * 32 + vf_base;
            vreg[p] = *(const bf16x8*)(Vt + (size_t)f * Mn + vgbase + vch * 8);
        }
    };
    auto STORE_LDS = [&]() {
#pragma unroll
        for (int p = 0; p < 8; p++) {
            int r = p * 8 + krow_base;
            int baddr = (r * 512 + kch * 16) ^ ((r & 7) << 4);
            *(bf16x8*)(klds + baddr) = kreg[p];
        }
#pragma unroll
        for (int p = 0; p < 8; p++) {
            int f = p * 32 + vf_base;
            int baddr = (f * 128 + vch * 16) ^ ((f & 7) << 4);
            *(bf16x8*)(vlds + baddr) = vreg[p];
        }
    };
    auto COMPUTE = [&](int t) {
        int kv0 = t * 64;
        // ---- S^T = K Q^T : lane holds S^T[kv=16n+4g+r][q=c] ----
        f32x4 s[4];
#pragma unroll
        for (int n = 0; n < 4; n++) s[n] = fz;
#pragma unroll
        for (int n = 0; n < 4; n++) {
            int kr = n * 16 + c;
            int swz = (kr & 7) << 4;
#pragma unroll
            for (int kk = 0; kk < 8; kk++) {
                bf16x8 kf = *(const bf16x8*)(klds + ((kr * 512 + kk * 64 + g * 16) ^ swz));
                s[n] = __builtin_amdgcn_mfma_f32_16x16x32_bf16(kf, qf[kk], s[n], 0, 0, 0);
            }
        }
        // ---- scale + causal mask (exp2 domain), per-lane softmax ----
        float t2[4][4];
        float tmax = -INFINITY;
#pragma unroll
        for (int n = 0; n < 4; n++)
#pragma unroll
            for (int r = 0; r < 4; r++) {
                float v = s[n][r] * C1;
                int kvg = kv0 + 16 * n + 4 * g + r;
                v = (kvg <= qg_lane) ? v : -INFINITY;
                t2[n][r] = v;
                tmax = fmaxf(tmax, v);
            }
        tmax = fmaxf(tmax, __shfl_xor(tmax, 16));
        tmax = fmaxf(tmax, __shfl_xor(tmax, 32));
        float mn = fmaxf(m2, tmax);
        float alpha = exp2f(m2 - mn);
        float p[4][4];
        float ps = 0.f;
#pragma unroll
        for (int n = 0; n < 4; n++)
#pragma unroll
            for (int r = 0; r < 4; r++) {
                float pv = exp2f(t2[n][r] - mn);
                p[n][r] = pv;
                ps += pv;
            }
        ps += __shfl_xor(ps, 16);
        ps += __shfl_xor(ps, 32);
        l = l * alpha + ps;
        m2 = mn;
#pragma unroll
        for (int n = 0; n < 16; n++) o[n] = o[n] * alpha;
        // ---- pack P to bf16 words: pk[n][h] = {p[n][2h], p[n][2h+1]} ----
        unsigned int pk[4][2];
#pragma unroll
        for (int n = 0; n < 4; n++)
#pragma unroll
            for (int hh = 0; hh < 2; hh++)
                pk[n][hh] = (unsigned int)f2bf(p[n][2 * hh]) |
                            ((unsigned int)f2bf(p[n][2 * hh + 1]) << 16);
        // ---- redistribute to P^T B-fragments: lane needs P[c][32s+8g+j] ----
        int srcbase = c + ((lane & 16) << 1);   // c + 16*2*(g&1)
        unsigned int pw[2][4];
#pragma unroll
        for (int s2 = 0; s2 < 2; s2++)
#pragma unroll
            for (int w4 = 0; w4 < 4; w4++) {
                int src = srcbase + ((w4 >> 1) << 4);
                unsigned int lo = (unsigned int)__shfl((int)pk[2 * s2][w4 & 1], src);
                unsigned int hi = (unsigned int)__shfl((int)pk[2 * s2 + 1][w4 & 1], src);
                pw[s2][w4] = (g >= 2) ? hi : lo;
            }
        union { unsigned int u[4]; bf16x8 v; } pf0, pf1;
#pragma unroll
        for (int w4 = 0; w4 < 4; w4++) { pf0.u[w4] = pw[0][w4]; pf1.u[w4] = pw[1][w4]; }
        // ---- O^T += V^T P^T ----
#pragma unroll
        for (int n = 0; n < 16; n++) {
            int f = n * 16 + c;
            int swz = (f & 7) << 4;
            bf16x8 vf0 = *(const bf16x8*)(vlds + ((f * 128 + 0 + g * 16) ^ swz));
            o[n] = __builtin_amdgcn_mfma_f32_16x16x32_bf16(vf0, pf0.v, o[n], 0, 0, 0);
            bf16x8 vf1 = *(const bf16x8*)(vlds + ((f * 128 + 64 + g * 16) ^ swz));
            o[n] = __builtin_amdgcn_mfma_f32_16x16x32_bf16(vf1, pf1.v, o[n], 0, 0, 0);
        }
    };

    int nt = qt + 1;
    LOADT(0);
    STORE_LDS();
    __syncthreads();
    for (int t = 1; t < nt; t++) {
        LOADT(t);            // prefetch into regs; latency hides under compute
        COMPUTE(t - 1);
        __syncthreads();     // all waves done reading LDS
        STORE_LDS();
        __syncthreads();
    }
    COMPUTE(nt - 1);

    // ---- epilogue: O^T -> row-major via LDS, coalesced f32x4 stores ----
    float inv = 1.0f / l;
    __syncthreads();
    float* eld = (float*)(smem + w * 8448);   // per-wave region 16 x 132 f32
#pragma unroll
    for (int h2 = 0; h2 < 2; h2++) {
#pragma unroll
        for (int n = 0; n < 8; n++) {
            f32x4 val = o[h2 * 8 + n] * inv;
            *(f32x4*)(eld + c * 132 + n * 16 + 4 * g) = val;
        }
#pragma unroll
        for (int tI = 0; tI < 4; tI++)
#pragma unroll
            for (int inner = 0; inner < 2; inner++) {
                f32x4 v = *(const f32x4*)(eld + (4 * tI + g) * 132 + inner * 64 + 4 * c);
                size_t oaddr = ((size_t)b * Tn + q0 + w * 16 + 4 * tI + g) * 256
                             + h2 * 128 + inner * 64 + 4 * c;
                *(f32x4*)(outp + oaddr) = v;
            }
        __syncthreads();   // region reuse between halves (cheap, 2x per kernel)
    }
}

extern "C" void kernel_launch(void* const* d_in, const int* in_sizes, int n_in,
                              void* d_out, int out_size, void* d_ws, size_t ws_size,
                              hipStream_t stream) {
    (void)in_sizes; (void)n_in; (void)out_size; (void)ws_size;
    const float* x  = (const float*)d_in[0];
    const float* wk = (const float*)d_in[1];
    const float* wq = (const float*)d_in[2];
    const float* wv = (const float*)d_in[3];
    float* outp = (float*)d_out;

    char* ws = (char*)d_ws;
    unsigned short* xb  = (unsigned short*)ws;                 // 16 MB
    unsigned short* wt  = (unsigned short*)(ws + 16777216);    // 384 KB [Wq, Wk, Wv]
    unsigned short* qkv = (unsigned short*)(ws + 17170432);    // 48 MB: [Q, K, V^T]

    cast_x_kernel<<<Mn * Dn / 8 / 256, 256, 0, stream>>>(x, xb);
    wt_kernel<<<3 * 65536 / 256, 256, 0, stream>>>(wq, wk, wv, wt);
    proj_kernel<<<dim3(Mn / 64, 3), 256, 0, stream>>>(xb, wt, qkv);
    attn_kernel<<<512, 256, 0, stream>>>(qkv, outp);
}

// Round 4
// 276.733 us; speedup vs baseline: 1.3417x; 1.3417x over previous
//
#include <hip/hip_runtime.h>

#define Bn 8
#define Tn 4096
#define Dn 256
#define Mn (Bn*Tn)           // 32768

typedef short bf16x8 __attribute__((ext_vector_type(8)));
typedef float f32x4 __attribute__((ext_vector_type(4)));

// ---- ws layout (bytes) ----
// phase A (cast/wt/proj): xb @0 (16 MB), wt @16 MB (384 KB)
// phase B (attn/combine): partials bf16 @0 (40 MB), ml float2 @41943040 (640 KB)
// persistent: qkv (Q, K, V^T bf16) @42598400 (48 MB)   -> total ~88.6 MB
#define P_OFF   0ul
#define ML_OFF  41943040ul
#define XB_OFF  0ul
#define WT_OFF  16777216ul
#define QKV_OFF 42598400ul

__device__ __forceinline__ unsigned short f2bf(float f) {
    union { float f; unsigned int u; } v; v.f = f;
    unsigned int r = v.u + 0x7fffu + ((v.u >> 16) & 1u);
    return (unsigned short)(r >> 16);
}
__device__ __forceinline__ float bf2f(unsigned short u) {
    union { unsigned int u; float f; } v; v.u = ((unsigned int)u) << 16;
    return v.f;
}

// ---------------- cast x (f32 -> bf16) ----------------
__global__ void __launch_bounds__(256) cast_x_kernel(const float* __restrict__ x,
                                                     unsigned short* __restrict__ xb) {
    size_t i = (size_t)blockIdx.x * 256 + threadIdx.x;
    const float4* p = reinterpret_cast<const float4*>(x) + i * 2;
    float4 a = p[0], b = p[1];
    union { unsigned short u[8]; uint4 v; } o;
    o.u[0]=f2bf(a.x); o.u[1]=f2bf(a.y); o.u[2]=f2bf(a.z); o.u[3]=f2bf(a.w);
    o.u[4]=f2bf(b.x); o.u[5]=f2bf(b.y); o.u[6]=f2bf(b.z); o.u[7]=f2bf(b.w);
    reinterpret_cast<uint4*>(xb)[i] = o.v;
}

// ---------------- W transpose+cast ----------------
__global__ void __launch_bounds__(256) wt_kernel(const float* __restrict__ wq,
                                                 const float* __restrict__ wk,
                                                 const float* __restrict__ wv,
                                                 unsigned short* __restrict__ wt) {
    int idx = blockIdx.x * 256 + threadIdx.x;
    int h = idx >> 16; int r = idx & 65535;
    int k = r >> 8, n = r & 255;
    const float* src = (h == 0) ? wq : (h == 1) ? wk : wv;
    wt[h * 65536 + n * 256 + k] = f2bf(src[k * 256 + n]);
}

// ---------------- projection GEMM: Q,K row-major; V transposed [256][M] ----------------
__global__ void __launch_bounds__(256, 2) proj_kernel(const unsigned short* __restrict__ xb,
                                                      const unsigned short* __restrict__ wt,
                                                      unsigned short* __restrict__ qkv) {
    __shared__ unsigned short wlds[256 * 40];
    int h = blockIdx.y;
    const unsigned short* wth = wt + h * 65536;
    int m0 = blockIdx.x * 64;
    int tid = threadIdx.x;
    int w = tid >> 6, lane = tid & 63;
    int c = lane & 15, g = lane >> 4;
    size_t arow = (size_t)(m0 + w * 16 + c);

    const f32x4 fz = {0.f, 0.f, 0.f, 0.f};
    f32x4 acc[16];
#pragma unroll
    for (int n = 0; n < 16; n++) acc[n] = fz;

    for (int kk = 0; kk < 8; kk++) {
        __syncthreads();
#pragma unroll
        for (int p = 0; p < 4; p++) {
            int idx = p * 256 + tid;
            int r = idx >> 2, ch = idx & 3;
            bf16x8 v = *(const bf16x8*)(wth + r * 256 + kk * 32 + ch * 8);
            *(bf16x8*)(&wlds[r * 40 + ch * 8]) = v;
        }
        __syncthreads();
        bf16x8 af = *(const bf16x8*)(xb + arow * Dn + kk * 32 + g * 8);
#pragma unroll
        for (int n = 0; n < 16; n++) {
            bf16x8 bfv = *(const bf16x8*)(&wlds[(n * 16 + c) * 40 + g * 8]);
            acc[n] = __builtin_amdgcn_mfma_f32_16x16x32_bf16(af, bfv, acc[n], 0, 0, 0);
        }
    }
    int orow0 = m0 + w * 16 + g * 4;
    if (h < 2) {
        unsigned short* out = qkv + (size_t)h * Mn * Dn;
#pragma unroll
        for (int n = 0; n < 16; n++)
#pragma unroll
            for (int r = 0; r < 4; r++)
                out[(size_t)(orow0 + r) * Dn + n * 16 + c] = f2bf(acc[n][r]);
    } else {
        unsigned short* vt = qkv + (size_t)2 * Mn * Dn;   // [256][M]
#pragma unroll
        for (int n = 0; n < 16; n++) {
            union { unsigned short u[4]; ushort4 v4; } pk;
#pragma unroll
            for (int r = 0; r < 4; r++) pk.u[r] = f2bf(acc[n][r]);
            *(ushort4*)(vt + (size_t)(n * 16 + c) * Mn + orow0) = pk.v4;
        }
    }
}

// ---------------- causal flash attention, KV-split into 1024-chunks ----------------
// 1280 blocks: bid = r*8 + b (batch fastest -> per-XCD K/V locality)
// r in [0,160): chunk cc via offsets {0,64,112,144}; j = r - off; qt = 63 - j (heavy first)
// block covers kv tiles [32cc, min(32cc+32, 2qt+2)) of KVBLK=32; writes bf16 partial + (m,l)
__global__ void __launch_bounds__(256) attn_kernel(const unsigned short* __restrict__ qkv,
                                                   unsigned short* __restrict__ part,
                                                   float2* __restrict__ ml) {
    __shared__ char smem[32768];
    char* klds = smem;            // K tile [32][256] bf16, XOR-swizzled (16 KB)
    char* vlds = smem + 16384;    // V^T tile [256][32] bf16, XOR-swizzled (16 KB)

    int bid = blockIdx.x;
    int b = bid & 7;
    int r = bid >> 3;             // 0..159
    int cc, j;
    if (r < 64)       { cc = 0; j = r; }
    else if (r < 112) { cc = 1; j = r - 64; }
    else if (r < 144) { cc = 2; j = r - 112; }
    else              { cc = 3; j = r - 144; }
    int qt = 63 - j;
    int slot = b * 160 + r;
    int q0 = qt * 64;

    int tid = threadIdx.x, w = tid >> 6, lane = tid & 63;
    int c = lane & 15, g = lane >> 4;

    const unsigned short* Qg = qkv;
    const unsigned short* Kg = qkv + (size_t)Mn * Dn;
    const unsigned short* Vt = qkv + (size_t)2 * Mn * Dn;

    int qrow = q0 + w * 16;
    int qg_lane = qrow + c;

    bf16x8 qf[8];
#pragma unroll
    for (int kk = 0; kk < 8; kk++)
        qf[kk] = *(const bf16x8*)(Qg + ((size_t)b * Tn + qrow + c) * Dn + kk * 32 + g * 8);

    const f32x4 fz = {0.f, 0.f, 0.f, 0.f};
    f32x4 o[16];
#pragma unroll
    for (int n = 0; n < 16; n++) o[n] = fz;
    float m2 = -INFINITY, l = 0.f;

    bf16x8 kreg[4], vreg[4];
    const float C1 = 0.09016844005555897f;   // (1/16) * log2(e)

    auto LOADT = [&](int t) {
        size_t kgbase = ((size_t)b * Tn + t * 32) * Dn;
        size_t vgbase = (size_t)b * Tn + t * 32;
#pragma unroll
        for (int p = 0; p < 4; p++) {
            int id = p * 256 + tid;
            int kr = id >> 5, ch = id & 31;
            kreg[p] = *(const bf16x8*)(Kg + kgbase + (size_t)kr * Dn + ch * 8);
        }
#pragma unroll
        for (int p = 0; p < 4; p++) {
            int id = p * 256 + tid;
            int f = id >> 2, ch = id & 3;
            vreg[p] = *(const bf16x8*)(Vt + (size_t)f * Mn + vgbase + ch * 8);
        }
    };
    auto STORE_LDS = [&]() {
#pragma unroll
        for (int p = 0; p < 4; p++) {
            int id = p * 256 + tid;
            int kr = id >> 5, ch = id & 31;
            *(bf16x8*)(klds + ((kr * 512 + ch * 16) ^ ((kr & 7) << 4))) = kreg[p];
        }
#pragma unroll
        for (int p = 0; p < 4; p++) {
            int id = p * 256 + tid;
            int f = id >> 2, ch = id & 3;
            *(bf16x8*)(vlds + ((f * 64 + ch * 16) ^ (((f >> 2) & 3) << 4))) = vreg[p];
        }
    };
    auto COMPUTE = [&](int t) {
        int kv0 = t * 32;
        f32x4 s0 = fz, s1 = fz;
        int swz = (c & 7) << 4;
        __builtin_amdgcn_s_setprio(1);
#pragma unroll
        for (int kk = 0; kk < 8; kk++) {
            bf16x8 kf0 = *(const bf16x8*)(klds + ((c * 512 + kk * 64 + g * 16) ^ swz));
            s0 = __builtin_amdgcn_mfma_f32_16x16x32_bf16(kf0, qf[kk], s0, 0, 0, 0);
            bf16x8 kf1 = *(const bf16x8*)(klds + (((16 + c) * 512 + kk * 64 + g * 16) ^ swz));
            s1 = __builtin_amdgcn_mfma_f32_16x16x32_bf16(kf1, qf[kk], s1, 0, 0, 0);
        }
        __builtin_amdgcn_s_setprio(0);
        // mask + scale (exp2 domain)
        float t2[2][4];
        float tmax = -INFINITY;
#pragma unroll
        for (int rr = 0; rr < 4; rr++) {
            float v0 = s0[rr] * C1, v1 = s1[rr] * C1;
            int kv_0 = kv0 + 4 * g + rr;
            v0 = (kv_0 <= qg_lane) ? v0 : -INFINITY;
            v1 = (kv_0 + 16 <= qg_lane) ? v1 : -INFINITY;
            t2[0][rr] = v0; t2[1][rr] = v1;
            tmax = fmaxf(tmax, fmaxf(v0, v1));
        }
        tmax = fmaxf(tmax, __shfl_xor(tmax, 16));
        tmax = fmaxf(tmax, __shfl_xor(tmax, 32));
        float mn = m2;
        if (!__all(tmax - m2 <= 8.0f)) {          // T13 defer-max
            mn = fmaxf(m2, tmax);
            float alpha = exp2f(m2 - mn);
            l *= alpha;
            m2 = mn;
#pragma unroll
            for (int n = 0; n < 16; n++) o[n] = o[n] * alpha;
        }
        float p[2][4];
        float ps = 0.f;
#pragma unroll
        for (int n = 0; n < 2; n++)
#pragma unroll
            for (int rr = 0; rr < 4; rr++) {
                float pv = exp2f(t2[n][rr] - mn);
                p[n][rr] = pv;
                ps += pv;
            }
        ps += __shfl_xor(ps, 16);
        ps += __shfl_xor(ps, 32);
        l += ps;
        // pack P pairs: pk[n][hs] = {p[n][2hs], p[n][2hs+1]}  (kv = 16n+4g'+2hs, +1)
        unsigned int pk[2][2];
#pragma unroll
        for (int n = 0; n < 2; n++)
#pragma unroll
            for (int hs = 0; hs < 2; hs++)
                pk[n][hs] = (unsigned int)f2bf(p[n][2 * hs]) |
                            ((unsigned int)f2bf(p[n][2 * hs + 1]) << 16);
        // redistribute: dest lane (c,g) word h holds P^T[kv=8g+2h,+1][q=c].
        // kv pair: 8g+2h = 16*(g>>1) + 4*gs + 2*(h&1), gs = 2*(g&1)+(h>>1).
        // NOTE: shfl value expr is evaluated on the SOURCE lane -> indices into
        // pk must be lane-uniform; select the n = g>>1 half on the dest side.
        union { unsigned int u[4]; bf16x8 v; } pf;
#pragma unroll
        for (int h = 0; h < 4; h++) {
            int gs = 2 * (g & 1) + (h >> 1);
            unsigned int lo = (unsigned int)__shfl((int)pk[0][h & 1], c + 16 * gs);
            unsigned int hi = (unsigned int)__shfl((int)pk[1][h & 1], c + 16 * gs);
            pf.u[h] = (g >= 2) ? hi : lo;
        }
        // O^T += V^T P^T
        __builtin_amdgcn_s_setprio(1);
#pragma unroll
        for (int n = 0; n < 16; n++) {
            int f = n * 16 + c;
            bf16x8 vf = *(const bf16x8*)(vlds + ((f * 64 + g * 16) ^ (((f >> 2) & 3) << 4)));
            o[n] = __builtin_amdgcn_mfma_f32_16x16x32_bf16(vf, pf.v, o[n], 0, 0, 0);
        }
        __builtin_amdgcn_s_setprio(0);
    };

    int t0 = cc * 32;
    int tend = min(cc * 32 + 32, 2 * qt + 2);
    LOADT(t0);
    STORE_LDS();
    __syncthreads();
    for (int t = t0 + 1; t < tend; t++) {
        LOADT(t);
        __builtin_amdgcn_sched_barrier(0);   // keep prefetch issued before compute
        COMPUTE(t - 1);
        __syncthreads();
        STORE_LDS();
        __syncthreads();
    }
    COMPUTE(tend - 1);

    // ---- write m,l ----
    if (g == 0)
        ml[slot * 64 + w * 16 + c] = make_float2(m2, l);

    // ---- epilogue: O^T -> row-major bf16 partial via per-wave LDS transpose ----
    __syncthreads();
    float* eld = (float*)(smem + w * 4352);   // 16 rows x 68 f32
    int rql = lane >> 2, cg4 = lane & 3;
#pragma unroll
    for (int ch4 = 0; ch4 < 4; ch4++) {
#pragma unroll
        for (int nn = 0; nn < 4; nn++)
            *(f32x4*)(eld + c * 68 + nn * 16 + 4 * g) = o[ch4 * 4 + nn];
        asm volatile("s_waitcnt lgkmcnt(0)" ::: "memory");
        __builtin_amdgcn_sched_barrier(0);
#pragma unroll
        for (int k = 0; k < 4; k++) {
            f32x4 v = *(const f32x4*)(eld + rql * 68 + cg4 * 16 + 4 * k);
            union { unsigned short u[4]; ushort4 v4; } pkk;
            pkk.u[0] = f2bf(v[0]); pkk.u[1] = f2bf(v[1]);
            pkk.u[2] = f2bf(v[2]); pkk.u[3] = f2bf(v[3]);
            *(ushort4*)(part + ((size_t)slot * 64 + w * 16 + rql) * 256
                             + ch4 * 64 + cg4 * 16 + 4 * k) = pkk.v4;
        }
        asm volatile("s_waitcnt lgkmcnt(0)" ::: "memory");
        __builtin_amdgcn_sched_barrier(0);
    }
}

// ---------------- combine partials ----------------
__global__ void __launch_bounds__(256) combine_kernel(const unsigned short* __restrict__ part,
                                                      const float2* __restrict__ ml,
                                                      float* __restrict__ out) {
    int row = blockIdx.x * 4 + (threadIdx.x >> 6);
    int fi = (threadIdx.x & 63) * 4;
    int b = row >> 12, q = row & 4095;
    int qt = q >> 6, qloc = q & 63;
    int nch = (qt >> 4) + 1;
    const int offt[4] = {0, 64, 112, 144};
    int slots[4]; float mv[4], lv[4];
    float M = -INFINITY;
    for (int ci = 0; ci < nch; ci++) {
        int slot = b * 160 + offt[ci] + (63 - qt);
        slots[ci] = slot;
        float2 p = ml[slot * 64 + qloc];
        mv[ci] = p.x; lv[ci] = p.y;
        M = fmaxf(M, p.x);
    }
    float L = 0.f;
    float a0 = 0.f, a1 = 0.f, a2 = 0.f, a3 = 0.f;
    for (int ci = 0; ci < nch; ci++) {
        float wgt = exp2f(mv[ci] - M);
        L += wgt * lv[ci];
        ushort4 u = *(const ushort4*)(part + ((size_t)slots[ci] * 64 + qloc) * 256 + fi);
        a0 += wgt * bf2f(u.x); a1 += wgt * bf2f(u.y);
        a2 += wgt * bf2f(u.z); a3 += wgt * bf2f(u.w);
    }
    float inv = 1.f / L;
    float4 ov = {a0 * inv, a1 * inv, a2 * inv, a3 * inv};
    *(float4*)(out + (size_t)row * 256 + fi) = ov;
}

extern "C" void kernel_launch(void* const* d_in, const int* in_sizes, int n_in,
                              void* d_out, int out_size, void* d_ws, size_t ws_size,
                              hipStream_t stream) {
    (void)in_sizes; (void)n_in; (void)out_size; (void)ws_size;
    const float* x  = (const float*)d_in[0];
    const float* wk = (const float*)d_in[1];
    const float* wq = (const float*)d_in[2];
    const float* wv = (const float*)d_in[3];
    float* outp = (float*)d_out;

    char* ws = (char*)d_ws;
    unsigned short* xb   = (unsigned short*)(ws + XB_OFF);
    unsigned short* wt   = (unsigned short*)(ws + WT_OFF);
    unsigned short* qkv  = (unsigned short*)(ws + QKV_OFF);
    unsigned short* part = (unsigned short*)(ws + P_OFF);
    float2*         mlp  = (float2*)(ws + ML_OFF);

    cast_x_kernel<<<Mn * Dn / 8 / 256, 256, 0, stream>>>(x, xb);
    wt_kernel<<<3 * 65536 / 256, 256, 0, stream>>>(wq, wk, wv, wt);
    proj_kernel<<<dim3(Mn / 64, 3), 256, 0, stream>>>(xb, wt, qkv);
    attn_kernel<<<1280, 256, 0, stream>>>(qkv, part, mlp);
    combine_kernel<<<Mn / 4, 256, 0, stream>>>(part, mlp, outp);
}

// Round 5
// 201.074 us; speedup vs baseline: 1.8466x; 1.3763x over previous
//
#include <hip/hip_runtime.h>

#define Bn 8
#define Tn 4096
#define Dn 256
#define Mn (Bn*Tn)           // 32768

typedef short bf16x8 __attribute__((ext_vector_type(8)));
typedef float f32x4 __attribute__((ext_vector_type(4)));
typedef float f32x16 __attribute__((ext_vector_type(16)));

// ---- ws layout (bytes) ----
// phase A: xb @0 (16 MB), wt @16 MB (384 KB)
// phase B: partials bf16 @0 (40 MB = 640 slots * 64 KB), ml float2 @41943040 (640 KB)
// persistent: qkv (Q, K, V^T bf16) @42598400 (48 MB)
#define P_OFF   0ul
#define ML_OFF  41943040ul
#define XB_OFF  0ul
#define WT_OFF  16777216ul
#define QKV_OFF 42598400ul

__device__ __forceinline__ unsigned short f2bf(float f) {
    union { float f; unsigned int u; } v; v.f = f;
    unsigned int r = v.u + 0x7fffu + ((v.u >> 16) & 1u);
    return (unsigned short)(r >> 16);
}
__device__ __forceinline__ float bf2f(unsigned short u) {
    union { unsigned int u; float f; } v; v.u = ((unsigned int)u) << 16;
    return v.f;
}
__device__ __forceinline__ unsigned int pk2(float a, float b) {
    return (unsigned int)f2bf(a) | ((unsigned int)f2bf(b) << 16);
}

typedef __attribute__((address_space(1))) const unsigned int* gas_p;
typedef __attribute__((address_space(3))) unsigned int* las_p;
__device__ __forceinline__ void g2lds16(const void* g, void* l) {
    // async global->LDS, 16B/lane; LDS dest = wave-uniform base + lane*16
    __builtin_amdgcn_global_load_lds((gas_p)g, (las_p)l, 16, 0, 0);
}

// ---------------- cast x (f32 -> bf16) ----------------
__global__ void __launch_bounds__(256) cast_x_kernel(const float* __restrict__ x,
                                                     unsigned short* __restrict__ xb) {
    size_t i = (size_t)blockIdx.x * 256 + threadIdx.x;
    const float4* p = reinterpret_cast<const float4*>(x) + i * 2;
    float4 a = p[0], b = p[1];
    union { unsigned short u[8]; uint4 v; } o;
    o.u[0]=f2bf(a.x); o.u[1]=f2bf(a.y); o.u[2]=f2bf(a.z); o.u[3]=f2bf(a.w);
    o.u[4]=f2bf(b.x); o.u[5]=f2bf(b.y); o.u[6]=f2bf(b.z); o.u[7]=f2bf(b.w);
    reinterpret_cast<uint4*>(xb)[i] = o.v;
}

// ---------------- W transpose+cast ----------------
__global__ void __launch_bounds__(256) wt_kernel(const float* __restrict__ wq,
                                                 const float* __restrict__ wk,
                                                 const float* __restrict__ wv,
                                                 unsigned short* __restrict__ wt) {
    int idx = blockIdx.x * 256 + threadIdx.x;
    int h = idx >> 16; int r = idx & 65535;
    int k = r >> 8, n = r & 255;
    const float* src = (h == 0) ? wq : (h == 1) ? wk : wv;
    wt[h * 65536 + n * 256 + k] = f2bf(src[k * 256 + n]);
}

// ---------------- projection GEMM: Q,K row-major; V transposed [256][M] ----------------
__global__ void __launch_bounds__(256, 2) proj_kernel(const unsigned short* __restrict__ xb,
                                                      const unsigned short* __restrict__ wt,
                                                      unsigned short* __restrict__ qkv) {
    __shared__ unsigned short wlds[256 * 40];
    int h = blockIdx.y;
    const unsigned short* wth = wt + h * 65536;
    int m0 = blockIdx.x * 64;
    int tid = threadIdx.x;
    int w = tid >> 6, lane = tid & 63;
    int c = lane & 15, g = lane >> 4;
    size_t arow = (size_t)(m0 + w * 16 + c);

    const f32x4 fz = {0.f, 0.f, 0.f, 0.f};
    f32x4 acc[16];
#pragma unroll
    for (int n = 0; n < 16; n++) acc[n] = fz;

    for (int kk = 0; kk < 8; kk++) {
        __syncthreads();
#pragma unroll
        for (int p = 0; p < 4; p++) {
            int idx = p * 256 + tid;
            int r = idx >> 2, ch = idx & 3;
            bf16x8 v = *(const bf16x8*)(wth + r * 256 + kk * 32 + ch * 8);
            *(bf16x8*)(&wlds[r * 40 + ch * 8]) = v;
        }
        __syncthreads();
        bf16x8 af = *(const bf16x8*)(xb + arow * Dn + kk * 32 + g * 8);
#pragma unroll
        for (int n = 0; n < 16; n++) {
            bf16x8 bfv = *(const bf16x8*)(&wlds[(n * 16 + c) * 40 + g * 8]);
            acc[n] = __builtin_amdgcn_mfma_f32_16x16x32_bf16(af, bfv, acc[n], 0, 0, 0);
        }
    }
    int orow0 = m0 + w * 16 + g * 4;
    if (h < 2) {
        unsigned short* out = qkv + (size_t)h * Mn * Dn;
#pragma unroll
        for (int n = 0; n < 16; n++)
#pragma unroll
            for (int r = 0; r < 4; r++)
                out[(size_t)(orow0 + r) * Dn + n * 16 + c] = f2bf(acc[n][r]);
    } else {
        unsigned short* vt = qkv + (size_t)2 * Mn * Dn;   // [256][M]
#pragma unroll
        for (int n = 0; n < 16; n++) {
            union { unsigned short u[4]; ushort4 v4; } pk;
#pragma unroll
            for (int r = 0; r < 4; r++) pk.u[r] = f2bf(acc[n][r]);
            *(ushort4*)(vt + (size_t)(n * 16 + c) * Mn + orow0) = pk.v4;
        }
    }
}

// ---------------- attention: 32x32x16 swapped, 128-row q-tiles, KV-split ----------------
// 640 blocks, bid = r*8+b. r in [0,80): heavy-first map to (qt' in [0,32), cc chunk of 32 tiles).
// Full chunks (32 tiles): r<24: qt'=24+(r&7),cc=r>>3; r<40: qt'=16+((r-24)&7),cc=(r-24)>>3;
// r<48: qt'=8+(r-40),cc=0. Partials: k=r-48: u=k>>2,v=k&3: qt'=8v+7-u, cc=v.
// Block covers kv tiles [32cc, min(32cc+32, 4(qt'+1))), KVBLK=32.
__global__ void __launch_bounds__(256, 2) attn_kernel(const unsigned short* __restrict__ qkv,
                                                      unsigned short* __restrict__ part,
                                                      float2* __restrict__ ml) {
    __shared__ char smem[65536];   // 2 bufs x (K 16KB + V^T 16KB)

    int bid = blockIdx.x;
    int b = bid & 7;
    int r = bid >> 3;
    int qtp, cc;
    if (r < 24)      { qtp = 24 + (r & 7); cc = r >> 3; }
    else if (r < 40) { int rp = r - 24; qtp = 16 + (rp & 7); cc = rp >> 3; }
    else if (r < 48) { qtp = 8 + (r - 40); cc = 0; }
    else             { int k = r - 48; int u = k >> 2, v = k & 3; qtp = 8 * v + 7 - u; cc = v; }
    int slot = b * 80 + r;

    int tid = threadIdx.x, w = tid >> 6, lane = tid & 63;
    int lq = lane & 31, hh = lane >> 5;

    const unsigned short* Qg = qkv;
    const unsigned short* Kg = qkv + (size_t)Mn * Dn;
    const unsigned short* Vt = qkv + (size_t)2 * Mn * Dn;

    int qrow = qtp * 128 + w * 32 + lq;          // lane's q (within batch)

    // Q fragments: B-operand, lane holds Q[qrow][16s + 8hh + j]
    bf16x8 qf[16];
#pragma unroll
    for (int s = 0; s < 16; s++)
        qf[s] = *(const bf16x8*)(Qg + ((size_t)b * Tn + qrow) * Dn + s * 16 + hh * 8);

    f32x16 o[8];
#pragma unroll
    for (int dg = 0; dg < 8; dg++)
#pragma unroll
        for (int e = 0; e < 16; e++) o[dg][e] = 0.f;
    float m2 = -INFINITY, lsum = 0.f;

    const float C1 = 0.09016844005555897f;       // (1/16) * log2(e)

    auto STAGE = [&](int bufsel, int t) {
        // K tile [32 rows][32 chunks16B], chunk stored at slot = chunk ^ row
        const unsigned short* kgb = Kg + ((size_t)b * Tn + t * 32) * Dn;
        char* kb = smem + bufsel * 32768 + w * 4096;
#pragma unroll
        for (int i = 0; i < 4; i++) {
            int row = w * 8 + i * 2 + hh;
            int chunk = lq ^ row;
            g2lds16(kgb + row * 256 + chunk * 8, kb + i * 1024);
        }
        // V^T tile [256 d][4 chunks16B], chunk kvc stored at slot = kvc ^ ((d>>3)&3)
        const unsigned short* vgb = Vt + (size_t)b * Tn + t * 32;
        char* vb = smem + bufsel * 32768 + 16384 + w * 4096;
#pragma unroll
        for (int i = 0; i < 4; i++) {
            int d = w * 64 + i * 16 + (lane >> 2);
            int kvc = (lane & 3) ^ ((d >> 3) & 3);
            g2lds16(vgb + (size_t)d * Mn + kvc * 8, vb + i * 1024);
        }
    };

    auto COMPUTE = [&](int bufsel, int t) {
        int kv0 = t * 32;
        const char* klds = smem + bufsel * 32768;
        const char* vlds = klds + 16384;
        // ---- S^T = K Q^T: lane holds S^T[kv][q=lq], kv = kv0+(rr&3)+8(rr>>2)+4hh ----
        f32x16 sv;
#pragma unroll
        for (int e = 0; e < 16; e++) sv[e] = 0.f;
        __builtin_amdgcn_s_setprio(1);
#pragma unroll
        for (int s = 0; s < 16; s++) {
            bf16x8 kf = *(const bf16x8*)(klds + lq * 512 + ((2 * s + hh) ^ lq) * 16);
            sv = __builtin_amdgcn_mfma_f32_32x32x16_bf16(kf, qf[s], sv, 0, 0, 0);
        }
        __builtin_amdgcn_s_setprio(0);
        // ---- mask + scale (exp2 domain) ----
        float pv[16];
        float tmax = -INFINITY;
#pragma unroll
        for (int rr = 0; rr < 16; rr++) {
            int kvl = kv0 + (rr & 3) + 8 * (rr >> 2) + 4 * hh;
            float v = sv[rr] * C1;
            v = (kvl <= qrow) ? v : -INFINITY;
            pv[rr] = v;
            tmax = fmaxf(tmax, v);
        }
        tmax = fmaxf(tmax, __shfl_xor(tmax, 32));
        float mn = m2;
        if (!__all(tmax - m2 <= 8.0f)) {          // T13 defer-max
            mn = fmaxf(m2, tmax);
            float alpha = exp2f(m2 - mn);
            lsum *= alpha;
            m2 = mn;
#pragma unroll
            for (int dg = 0; dg < 8; dg++) o[dg] = o[dg] * alpha;
        }
        float ps = 0.f;
#pragma unroll
        for (int rr = 0; rr < 16; rr++) {
            pv[rr] = exp2f(pv[rr] - mn);
            ps += pv[rr];
        }
        ps += __shfl_xor(ps, 32);
        lsum += ps;
        // ---- P^T B-fragments. Per k-step s2: lane needs P[q=lq][kv=16s2+8hh+j].
        // Owned: regs 8s2+k' hold kv = 16s2 + (k'&3) + 8(k'>>2) + 4hh.
        // Exchange halves with source-side select: e0 = hh? w0 : y0 etc. ----
        union U4 { unsigned int u[4]; bf16x8 v; };
        U4 fr[2];
#pragma unroll
        for (int s2 = 0; s2 < 2; s2++) {
            int bidx = 8 * s2;
            unsigned int w0 = pk2(pv[bidx + 0], pv[bidx + 1]);
            unsigned int w1 = pk2(pv[bidx + 2], pv[bidx + 3]);
            unsigned int y0 = pk2(pv[bidx + 4], pv[bidx + 5]);
            unsigned int y1 = pk2(pv[bidx + 6], pv[bidx + 7]);
            unsigned int e0 = hh ? w0 : y0;
            unsigned int e1 = hh ? w1 : y1;
            unsigned int x0 = (unsigned int)__shfl_xor((int)e0, 32);
            unsigned int x1 = (unsigned int)__shfl_xor((int)e1, 32);
            fr[s2].u[0] = hh ? x0 : w0;
            fr[s2].u[1] = hh ? x1 : w1;
            fr[s2].u[2] = hh ? y0 : x0;
            fr[s2].u[3] = hh ? y1 : x1;
        }
        // ---- O^T += V^T P^T ----
        __builtin_amdgcn_s_setprio(1);
#pragma unroll
        for (int dg = 0; dg < 8; dg++) {
            int d = 32 * dg + lq;
            int swz = (d >> 3) & 3;
#pragma unroll
            for (int s2 = 0; s2 < 2; s2++) {
                bf16x8 vf = *(const bf16x8*)(vlds + d * 64 + ((2 * s2 + hh) ^ swz) * 16);
                o[dg] = __builtin_amdgcn_mfma_f32_32x32x16_bf16(vf, fr[s2].v, o[dg], 0, 0, 0);
            }
        }
        __builtin_amdgcn_s_setprio(0);
    };

    int t0 = cc * 32;
    int tend = min(t0 + 32, 4 * (qtp + 1));
    int cur = 0;
    STAGE(0, t0);
    __syncthreads();
    for (int t = t0; t < tend; t++) {
        if (t + 1 < tend) STAGE(cur ^ 1, t + 1);
        COMPUTE(cur, t);
        __syncthreads();
        cur ^= 1;
    }

    // ---- m,l ----
    if (hh == 0)
        ml[(size_t)slot * 128 + w * 32 + lq] = make_float2(m2, lsum);

    // ---- partial store, register-native packed layout:
    // part[slot][w][dg][h2][lane] = uint4 of dwords j=4h2..4h2+3, dword j = pk(o[2j],o[2j+1]) ----
    uint4* pb = (uint4*)part;
#pragma unroll
    for (int dg = 0; dg < 8; dg++) {
        uint4 lo, hi2;
        lo.x = pk2(o[dg][0], o[dg][1]);  lo.y = pk2(o[dg][2], o[dg][3]);
        lo.z = pk2(o[dg][4], o[dg][5]);  lo.w = pk2(o[dg][6], o[dg][7]);
        hi2.x = pk2(o[dg][8], o[dg][9]);  hi2.y = pk2(o[dg][10], o[dg][11]);
        hi2.z = pk2(o[dg][12], o[dg][13]); hi2.w = pk2(o[dg][14], o[dg][15]);
        size_t base = (size_t)slot * 4096 + w * 1024 + dg * 128 + lane;
        pb[base] = lo;
        pb[base + 64] = hi2;
    }
}

// ---------------- combine ----------------
// 1024 blocks: bid -> b = bid&7, rest = bid>>3: qt' = rest>>2, w = rest&3.
__global__ void __launch_bounds__(256) combine_kernel(const unsigned short* __restrict__ part,
                                                      const float2* __restrict__ ml,
                                                      float* __restrict__ out) {
    __shared__ float2 mls[4][32];
    int bid = blockIdx.x;
    int b = bid & 7;
    int rest = bid >> 3;
    int qtp = rest >> 2, w = rest & 3;
    int nch = (qtp >> 3) + 1;
    int tid = threadIdx.x;

    // slot r for (qtp, ci)
    int slots[4];
#pragma unroll
    for (int ci = 0; ci < 4; ci++) {
        int rr;
        if (ci == nch - 1)       rr = 48 + 4 * (7 - (qtp & 7)) + (qtp >> 3);
        else if (qtp >= 24)      rr = 8 * ci + (qtp - 24);
        else if (qtp >= 16)      rr = 24 + 8 * ci + (qtp - 16);
        else                     rr = 40 + (qtp - 8);
        slots[ci] = b * 80 + rr;
    }
    if (tid < nch * 32) {
        int ci = tid >> 5, qq = tid & 31;
        mls[ci][qq] = ml[(size_t)slots[ci] * 128 + w * 32 + qq];
    }
    __syncthreads();

    int dg = tid >> 5, h2 = (tid >> 4) & 1, ls = tid & 15;
    const uint4* pb = (const uint4*)part;

    for (int rd = 0; rd < 4; rd++) {
        int lane_idx = ls + 16 * rd;
        int q = lane_idx & 31, hh = lane_idx >> 5;
        float M = -INFINITY;
#pragma unroll
        for (int ci = 0; ci < 4; ci++)
            if (ci < nch) M = fmaxf(M, mls[ci][q].x);
        float L = 0.f, wgt[4];
#pragma unroll
        for (int ci = 0; ci < 4; ci++) {
            if (ci < nch) { wgt[ci] = exp2f(mls[ci][q].x - M); L += wgt[ci] * mls[ci][q].y; }
            else wgt[ci] = 0.f;
        }
        float inv = 1.f / L;
        float a[8];
#pragma unroll
        for (int e = 0; e < 8; e++) a[e] = 0.f;
#pragma unroll
        for (int ci = 0; ci < 4; ci++) {
            if (ci >= nch) break;
            uint4 u = pb[(size_t)slots[ci] * 4096 + w * 1024 + dg * 128 + h2 * 64 + lane_idx];
            float wg = wgt[ci];
            a[0] += wg * bf2f((unsigned short)(u.x & 0xffff));
            a[1] += wg * bf2f((unsigned short)(u.x >> 16));
            a[2] += wg * bf2f((unsigned short)(u.y & 0xffff));
            a[3] += wg * bf2f((unsigned short)(u.y >> 16));
            a[4] += wg * bf2f((unsigned short)(u.z & 0xffff));
            a[5] += wg * bf2f((unsigned short)(u.z >> 16));
            a[6] += wg * bf2f((unsigned short)(u.w & 0xffff));
            a[7] += wg * bf2f((unsigned short)(u.w >> 16));
        }
        size_t row = (size_t)b * Tn + qtp * 128 + w * 32 + q;
        int dbase = 32 * dg + 16 * h2 + 4 * hh;
        float4 A = {a[0] * inv, a[1] * inv, a[2] * inv, a[3] * inv};
        float4 Bv = {a[4] * inv, a[5] * inv, a[6] * inv, a[7] * inv};
        *(float4*)(out + row * 256 + dbase) = A;
        *(float4*)(out + row * 256 + dbase + 8) = Bv;
    }
}

extern "C" void kernel_launch(void* const* d_in, const int* in_sizes, int n_in,
                              void* d_out, int out_size, void* d_ws, size_t ws_size,
                              hipStream_t stream) {
    (void)in_sizes; (void)n_in; (void)out_size; (void)ws_size;
    const float* x  = (const float*)d_in[0];
    const float* wk = (const float*)d_in[1];
    const float* wq = (const float*)d_in[2];
    const float* wv = (const float*)d_in[3];
    float* outp = (float*)d_out;

    char* ws = (char*)d_ws;
    unsigned short* xb   = (unsigned short*)(ws + XB_OFF);
    unsigned short* wt   = (unsigned short*)(ws + WT_OFF);
    unsigned short* qkv  = (unsigned short*)(ws + QKV_OFF);
    unsigned short* part = (unsigned short*)(ws + P_OFF);
    float2*         mlp  = (float2*)(ws + ML_OFF);

    cast_x_kernel<<<Mn * Dn / 8 / 256, 256, 0, stream>>>(x, xb);
    wt_kernel<<<3 * 65536 / 256, 256, 0, stream>>>(wq, wk, wv, wt);
    proj_kernel<<<dim3(Mn / 64, 3), 256, 0, stream>>>(xb, wt, qkv);
    attn_kernel<<<640, 256, 0, stream>>>(qkv, part, mlp);
    combine_kernel<<<1024, 256, 0, stream>>>(part, mlp, outp);
}